// Round 7
// baseline (533.731 us; speedup 1.0000x reference)
//
#include <hip/hip_runtime.h>

// VQ codebook: z_e (262144, 64) f32, embeddings (512, 64) f32.
// Outputs (flat f32 in d_out): z_q_st [N*D], indices-as-float [N], loss [1].
//
// R7: z row in 16 NAMED float4 regs across ALL panels (no re-reads) + acc[32]
// panel + SGPR-broadcast embT rows. ~110 VGPR/thread.
// R6 lesson: 16 z re-reads/token = 850MB beyond-L2 traffic = the wall
// (2.4TB/s * 350us). R1-R4 lesson: default occupancy target caps VGPR at 64
// and spills; R5 evidence: when LDS limits blocks/CU, the allocator exceeds
// 64 freely (used 88). So we FORCE the budget: 38KB dummy-sized LDS -> 4
// blocks/CU -> target 4 waves/EU -> VGPR budget 128 -> no spill, 16 waves/CU.

static constexpr int N_TOK   = 262144;
static constexpr int K       = 512;
static constexpr int D       = 64;
static constexpr int BLK     = 256;
static constexpr int NBLK    = N_TOK / BLK;  // 1024
static constexpr int PANEL   = 32;
static constexpr int NPANEL  = K / PANEL;    // 16

// ---- prep 0: esq[k] = ||e_k||^2 --------------------------------------------
__global__ void esq_kernel(const float* __restrict__ emb, float* __restrict__ esq) {
  int k = threadIdx.x;
  if (k < K) {
    const float4* row = reinterpret_cast<const float4*>(emb + (size_t)k * D);
    float s = 0.f;
#pragma unroll
    for (int i = 0; i < D / 4; ++i) {
      float4 v = row[i];
      s = fmaf(v.x, v.x, s);
      s = fmaf(v.y, v.y, s);
      s = fmaf(v.z, v.z, s);
      s = fmaf(v.w, v.w, s);
    }
    esq[k] = s;
  }
}

// ---- prep 1: embT[d][c] = emb[c][d] ----------------------------------------
__global__ __launch_bounds__(512) void embT_kernel(
    const float* __restrict__ emb, float* __restrict__ embT) {
  int idx = blockIdx.x * 512 + threadIdx.x;  // 64 blocks x 512
  int d = idx >> 9;
  int c = idx & 511;
  embT[idx] = emb[c * D + d];
}

// ---- main: per-token argmin + gather + partial loss ------------------------
__global__ __launch_bounds__(BLK) void vq_main(
    const float* __restrict__ z_e, const float* __restrict__ emb,
    const float* __restrict__ embT, const float* __restrict__ esq,
    float* __restrict__ out_zq, float* __restrict__ out_idx,
    float* __restrict__ block_loss) {
  // 38912 B: caps at 4 blocks/CU -> occupancy target 4 waves/EU -> VGPR
  // budget 128 (the R5-observed allocator behavior). Only [0,BLK) is used.
  __shared__ float red[9728];

  const int t = threadIdx.x;
  const int n = blockIdx.x * BLK + t;

  // Token row: 16 named float4 registers, loaded ONCE.
  const float4* zr = reinterpret_cast<const float4*>(z_e + (size_t)n * D);
  float4 z0  = zr[0],  z1  = zr[1],  z2  = zr[2],  z3  = zr[3];
  float4 z4  = zr[4],  z5  = zr[5],  z6  = zr[6],  z7  = zr[7];
  float4 z8  = zr[8],  z9  = zr[9],  z10 = zr[10], z11 = zr[11];
  float4 z12 = zr[12], z13 = zr[13], z14 = zr[14], z15 = zr[15];

  float best = 3.402823466e38f;
  int   bidx = 0;

// One d-row: e (wave-uniform -> s_load, SGPR operand) x zd (VGPR) -> acc.
#define ROW(DD, ZS)                                                  \
  {                                                                  \
    const float* e_ = Ep + (size_t)(DD) * K;                         \
    float zd_ = (ZS);                                                \
    _Pragma("unroll")                                                \
    for (int c = 0; c < PANEL; ++c) acc[c] = fmaf(zd_, e_[c], acc[c]); \
  }
#define DQUAD(I, ZQ) \
  ROW(4 * (I) + 0, (ZQ).x) ROW(4 * (I) + 1, (ZQ).y) \
  ROW(4 * (I) + 2, (ZQ).z) ROW(4 * (I) + 3, (ZQ).w)

  for (int p = 0; p < NPANEL; ++p) {
    const float* Ep = embT + p * PANEL;  // row stride K; wave-uniform
    float acc[PANEL];
#pragma unroll
    for (int c = 0; c < PANEL; ++c) acc[c] = 0.f;

    // d ascending 0..63 == R5/R6 accumulation order (absmax 0 heritage).
    DQUAD(0, z0)   DQUAD(1, z1)   DQUAD(2, z2)   DQUAD(3, z3)
    DQUAD(4, z4)   DQUAD(5, z5)   DQUAD(6, z6)   DQUAD(7, z7)
    DQUAD(8, z8)   DQUAD(9, z9)   DQUAD(10, z10) DQUAD(11, z11)
    DQUAD(12, z12) DQUAD(13, z13) DQUAD(14, z14) DQUAD(15, z15)

    const float* es = esq + p * PANEL;  // wave-uniform
#pragma unroll
    for (int c = 0; c < PANEL; ++c) {
      float s = fmaf(-2.f, acc[c], es[c]);
      // Ascending panel/c order + strict < == jnp.argmin first-min ties.
      if (s < best) { best = s; bidx = p * PANEL + c; }
    }
  }
#undef DQUAD
#undef ROW

  // Gather chosen code (divergent, codebook L2-hot); st = z + (q - z)
  // literally, z from registers (bitwise same values as input).
  float lsum = 0.f;
  {
    const float4* er = reinterpret_cast<const float4*>(emb + (size_t)bidx * D);
    float4* orow = reinterpret_cast<float4*>(out_zq + (size_t)n * D);
#define TAIL(i, ZI)                                        \
    {                                                      \
      float4 q = er[i];                                    \
      float dx = q.x - ZI.x, dy = q.y - ZI.y;              \
      float dz = q.z - ZI.z, dw = q.w - ZI.w;              \
      float4 st;                                           \
      st.x = ZI.x + dx; st.y = ZI.y + dy;                  \
      st.z = ZI.z + dz; st.w = ZI.w + dw;                  \
      orow[i] = st;                                        \
      lsum = fmaf(dx, dx, lsum);                           \
      lsum = fmaf(dy, dy, lsum);                           \
      lsum = fmaf(dz, dz, lsum);                           \
      lsum = fmaf(dw, dw, lsum);                           \
    }
    TAIL(0, z0)   TAIL(1, z1)   TAIL(2, z2)   TAIL(3, z3)
    TAIL(4, z4)   TAIL(5, z5)   TAIL(6, z6)   TAIL(7, z7)
    TAIL(8, z8)   TAIL(9, z9)   TAIL(10, z10) TAIL(11, z11)
    TAIL(12, z12) TAIL(13, z13) TAIL(14, z14) TAIL(15, z15)
#undef TAIL
  }

  out_idx[n] = (float)bidx;

  // Deterministic per-block loss reduction.
  red[t] = lsum;
  __syncthreads();
#pragma unroll
  for (int off = BLK / 2; off > 0; off >>= 1) {
    if (t < off) red[t] += red[t + off];
    __syncthreads();
  }
  if (t == 0) block_loss[blockIdx.x] = red[0];
}

// ---- finalize loss (deterministic tree) ------------------------------------
__global__ __launch_bounds__(256) void loss_finalize(
    const float* __restrict__ bl, float* __restrict__ out_loss) {
  __shared__ float sm[256];
  float s = 0.f;
  for (int i = threadIdx.x; i < NBLK; i += 256) s += bl[i];
  sm[threadIdx.x] = s;
  __syncthreads();
#pragma unroll
  for (int off = 128; off > 0; off >>= 1) {
    if (threadIdx.x < off) sm[threadIdx.x] += sm[threadIdx.x + off];
    __syncthreads();
  }
  if (threadIdx.x == 0) out_loss[0] = sm[0] * (1.0f / 16777216.0f);  // /(N*D)
}

extern "C" void kernel_launch(void* const* d_in, const int* in_sizes, int n_in,
                              void* d_out, int out_size, void* d_ws, size_t ws_size,
                              hipStream_t stream) {
  const float* z_e = (const float*)d_in[0];
  const float* emb = (const float*)d_in[1];

  float* out      = (float*)d_out;
  float* out_zq   = out;                          // N*D
  float* out_idx  = out + (size_t)N_TOK * D;      // N
  float* out_loss = out_idx + N_TOK;              // 1

  float* esq  = (float*)d_ws;            // K floats
  float* bl   = esq + K;                 // NBLK floats
  float* embT = bl + NBLK;               // K*D floats (128 KiB)

  esq_kernel<<<1, K, 0, stream>>>(emb, esq);
  embT_kernel<<<(K * D) / 512, 512, 0, stream>>>(emb, embT);
  vq_main<<<NBLK, BLK, 0, stream>>>(z_e, emb, embT, esq, out_zq, out_idx, bl);
  loss_finalize<<<1, 256, 0, stream>>>(bl, out_loss);
}